// Round 4
// baseline (4913.468 us; speedup 1.0000x reference)
//
#include <hip/hip_runtime.h>
#include <cstdint>

#define TT 512

typedef unsigned short u16;
typedef uint32_t u32;
typedef float  floatx4 __attribute__((ext_vector_type(4)));
typedef short  short8  __attribute__((ext_vector_type(8)));
typedef u32    u32x4   __attribute__((ext_vector_type(4)));

__device__ __forceinline__ float bf2f(u16 u) {
    union { u32 i; float f; } v; v.i = ((u32)u) << 16; return v.f;
}
__device__ __forceinline__ u16 f2bf(float f) {
    union { float f; u32 i; } v; v.f = f;
    u32 x = v.i;
    return (u16)((x + 0x7fffu + ((x >> 16) & 1u)) >> 16);  // RNE
}
__device__ __forceinline__ float sigm(float x)  { return 1.0f / (1.0f + __expf(-x)); }
__device__ __forceinline__ float tanh_(float x) { return 2.0f / (1.0f + __expf(-2.0f * x)) - 1.0f; }
#define BF(p) (*(const short8*)(p))

// ---- coherence recipe (r1-r3 measured):
// data stores/loads: sc1 (agent scope). Stores write through L2 to fabric;
// same-XCD consumers hit the shared L2 (202MB FETCH << 2GB issued, r3).
// sync counter: device-scope atomicAdd (executes at MALL, fire-and-forget),
// polled with sc0sc1 system-scope loads (guaranteed fresh, r1-proven).
// sc0-only is NOT coherent for cross-CU polling (r2: stale L1, spin timeout).
__device__ __forceinline__ void st32_dev(u32* p, u32 v) {
    asm volatile("global_store_dword %0, %1, off sc1" :: "v"(p), "v"(v) : "memory");
}
__device__ __forceinline__ void stf_dev(float* p, float v) {
    asm volatile("global_store_dword %0, %1, off sc1" :: "v"(p), "v"(v) : "memory");
}
__device__ __forceinline__ u32 ld32_poll_sys(const u32* p) {       // self-waiting (spin)
    u32 v;
    asm volatile("global_load_dword %0, %1, off sc0 sc1\n\ts_waitcnt vmcnt(0)"
                 : "=v"(v) : "v"(p) : "memory");
    return v;
}
__device__ __forceinline__ u32x4 ld128_dev(const u32x4* p) {       // pipelined: no wait
    u32x4 v;
    asm volatile("global_load_dwordx4 %0, %1, off sc1" : "=v"(v) : "v"(p));
    return v;
}
__device__ __forceinline__ float ldf_dev(const float* p) {         // pipelined: no wait
    float v;
    asm volatile("global_load_dword %0, %1, off sc1" : "=v"(v) : "v"(p));
    return v;
}
__device__ __forceinline__ void vmcnt0() { asm volatile("s_waitcnt vmcnt(0)" ::: "memory"); }
#define KEEP(x) asm volatile("" : "+v"(x))   // consume-after-wait fence (rule #18)

__global__ void zero_flags(u32* flg) {       // system scope, one-time: 512 u32 = 16 lines
    asm volatile("global_store_dword %0, %1, off sc0 sc1" :: "v"(&flg[threadIdx.x]), "v"(0u) : "memory");
}

#define MFMA_(A_, B_, ACC) ACC = __builtin_amdgcn_mfma_f32_16x16x32_bf16(A_, B_, ACC, 0, 0, 0)
#define MS1(ACC, GATE_) { short8 A_ = BF(fs0 + (GATE_) * 4096); \
    MFMA_(A_, Bh, ACC); MFMA_(A_, Bl, ACC); }
#define MS3(ACC, GATE_) { short8 A1_ = BF(fs1 + (GATE_) * 4096); \
    MFMA_(A1_, Bh, ACC); MFMA_(A1_, Bl, ACC); \
    short8 A2_ = BF(fs2 + (GATE_) * 4096); \
    MFMA_(A2_, Ch, ACC); MFMA_(A2_, Cl, ACC); }

// layer-0 gate: update c0, publish packed h0(p+1) via device-scope store
#define GATE0(R) { \
    const int d_ = dg16 + 4 * q + (R); \
    float zi_ = Zi[R] + b0s[0][d_], zf_ = Zf[R] + b0s[1][d_]; \
    float zg_ = Zg[R] + b0s[2][d_], zo_ = Zo[R] + b0s[3][d_]; \
    float c_  = sigm(zf_) * c0v[R] + sigm(zi_) * tanh_(zg_); c0v[R] = c_; \
    float hv_ = sigm(zo_) * tanh_(c_); \
    u16 hi_ = f2bf(hv_); u16 lo_ = f2bf(hv_ - bf2f(hi_)); \
    st32_dev(&hx0w[d_ * 16 + bq], ((u32)hi_ << 16) | (u32)lo_); }
#define GATE1L(R) { \
    const int d_ = dg16 + 4 * q + (R); \
    float zi_ = Yi[R] + b1s[0][d_], zf_ = Yf[R] + b1s[1][d_]; \
    float zg_ = Yg[R] + b1s[2][d_], zo_ = Yo[R] + b1s[3][d_]; \
    float c_  = sigm(zf_) * c1v[R] + sigm(zi_) * tanh_(zg_); c1v[R] = c_; \
    float hv_ = sigm(zo_) * tanh_(c_); \
    u16 hi_ = f2bf(hv_); u16 lo_ = f2bf(hv_ - bf2f(hi_)); \
    st32_dev(&hx1w[d_ * 16 + bq], ((u32)hi_ << 16) | (u32)lo_); \
    part += hv_ * who_s[d_]; }

#define UNPACK0(v, i4) { const int d_ = (i4) >> 2, bb_ = ((i4) & 3) * 4; \
    h0hi[bb_ + 0][d_] = (short)((v)[0] >> 16); h0lo[bb_ + 0][d_] = (short)((v)[0] & 0xFFFFu); \
    h0hi[bb_ + 1][d_] = (short)((v)[1] >> 16); h0lo[bb_ + 1][d_] = (short)((v)[1] & 0xFFFFu); \
    h0hi[bb_ + 2][d_] = (short)((v)[2] >> 16); h0lo[bb_ + 2][d_] = (short)((v)[2] & 0xFFFFu); \
    h0hi[bb_ + 3][d_] = (short)((v)[3] >> 16); h0lo[bb_ + 3][d_] = (short)((v)[3] & 0xFFFFu); }
#define UNPACK1(v, i4) { const int d_ = (i4) >> 2, bb_ = ((i4) & 3) * 4; \
    h1hi[bb_ + 0][d_] = (short)((v)[0] >> 16); h1lo[bb_ + 0][d_] = (short)((v)[0] & 0xFFFFu); \
    h1hi[bb_ + 1][d_] = (short)((v)[1] >> 16); h1lo[bb_ + 1][d_] = (short)((v)[1] & 0xFFFFu); \
    h1hi[bb_ + 2][d_] = (short)((v)[2] >> 16); h1lo[bb_ + 2][d_] = (short)((v)[2] & 0xFFFFu); \
    h1hi[bb_ + 3][d_] = (short)((v)[3] >> 16); h1lo[bb_ + 3][d_] = (short)((v)[3] & 0xFFFFu); }

// 128 blocks = 16 groups x 8 dim-slices. Skewed pipeline, 2 barriers/phase:
//   compute (hx + posc sc1 stores inline) -> per-wave vmcnt(0) ->
//   per-wave atomicAdd(cnt[g], 1) -> per-wave spin until cnt >= 32*(p+1)
//   -> per-wave readback ISSUE (overlaps barrier) -> bar
//   -> vmcnt(0) -> unpack to LDS -> out -> bar.
// cnt[g] lives on its own 128B line (no cross-group false sharing).
__launch_bounds__(256, 2)
__global__ void lstm_skew(const float* __restrict__ latent, const float* __restrict__ W_lh,
                          const float* __restrict__ b_lh,
                          const float* __restrict__ W_hh0,
                          const float* __restrict__ b_ih0, const float* __restrict__ b_hh0,
                          const float* __restrict__ W_ih1, const float* __restrict__ W_hh1,
                          const float* __restrict__ b_ih1, const float* __restrict__ b_hh1,
                          const float* __restrict__ W_ho,  const float* __restrict__ b_ho,
                          short* __restrict__ frag, u32* __restrict__ hx0, u32* __restrict__ hx1,
                          float* __restrict__ posc, u32* __restrict__ flg,
                          float* __restrict__ out)
{
    __shared__ __align__(16) short h0hi[16][264], h0lo[16][264];   // h0(p), full 256 dims
    __shared__ __align__(16) short h1hi[16][264], h1lo[16][264];   // h1(p-1)
    __shared__ float b0s[4][256], b1s[4][256];
    __shared__ float who_s[256];

    const int tid  = threadIdx.x;      // 256 threads, 4 waves
    const int w    = tid >> 6;
    const int lane = tid & 63;
    const int bq   = lane & 15;
    const int q    = lane >> 4;
    const int g    = blockIdx.x & 15;  // batch group
    const int j    = blockIdx.x >> 4;  // dim slice 0..7
    const int bglo = g * 16;

    // ---- stage this slice's weight fragments (identical bytes across groups: benign race)
    for (int i = tid; i < 12288; i += 256) {
        const int l8 = i & 63, s8 = (i >> 6) & 7, gate8 = (i >> 9) & 3;
        const int dgl = (i >> 11) & 1, G = i >> 12;
        const int dgw = 2 * j + dgl;
        const float* W = (G == 0) ? W_hh0 : (G == 1) ? W_ih1 : W_hh1;
        const float* src = W + (gate8 * 256 + dgw * 16 + (l8 & 15)) * 256
                             + s8 * 32 + (l8 >> 4) * 8;
        short8 v;
#pragma unroll
        for (int jj = 0; jj < 8; ++jj) v[jj] = (short)f2bf(src[jj]);
        *(short8*)(frag + (size_t)(l8 * 8 + s8 * 512 + gate8 * 4096 + dgw * 16384 + G * 262144)) = v;
    }
    for (int i = tid; i < 1024; i += 256) {
        b0s[i >> 8][i & 255] = b_ih0[i] + b_hh0[i];
        b1s[i >> 8][i & 255] = b_ih1[i] + b_hh1[i];
    }
    if (tid < 256) who_s[tid] = W_ho[tid];

    // h_init = latent @ W_lh.T + b_lh (fp32), split hi/lo
    {
        const int b = tid >> 4, d0 = (tid & 15) * 16;
        const float* lr = latent + (bglo + b) * 128;
#pragma unroll
        for (int jj = 0; jj < 16; ++jj) {
            const int d = d0 + jj;
            const float* wr = W_lh + d * 128;
            float acc = b_lh[d];
            for (int c = 0; c < 128; c += 4) {
                float4 lv = *(const float4*)(lr + c);
                float4 wv = *(const float4*)(wr + c);
                acc += lv.x * wv.x + lv.y * wv.y + lv.z * wv.z + lv.w * wv.w;
            }
            u16 hi = f2bf(acc), lo = f2bf(acc - bf2f(hi));
            h0hi[b][d] = (short)hi; h0lo[b][d] = (short)lo;
            h1hi[b][d] = (short)hi; h1lo[b][d] = (short)lo;
        }
    }
    __syncthreads();

    // wave roles: w0,w1 = layer 0 (dim-groups 2j, 2j+1); w2,w3 = layer 1
    const int dgw   = 2 * j + (w & 1);
    const int dg16  = dgw * 16;
    const short* fb0 = frag + dgw * 16384 + (size_t)lane * 8;
    const short* fb1 = frag + 262144 + dgw * 16384 + (size_t)lane * 8;
    const short* fb2 = fb1 + 262144;
    u32* cnt = flg + g * 32;           // group counter, own 128B line
    float c0v[4] = {0.f, 0.f, 0.f, 0.f}, c1v[4] = {0.f, 0.f, 0.f, 0.f};
    const float bho = b_ho[0];

    for (int p = 0; p <= TT; ++p) {
        const int pb = p & 1;
        u32* hx0w = hx0 + pb * 65536 + g * 4096;
        u32* hx1w = hx1 + pb * 65536 + g * 4096;
        float* poscw = posc + pb * 4096 + g * 256;   // [j][half][16]

        if (w < 2 && p < TT) {          // layer 0
            floatx4 Zi = {0.f,0.f,0.f,0.f}, Zf = {0.f,0.f,0.f,0.f};
            floatx4 Zg = {0.f,0.f,0.f,0.f}, Zo = {0.f,0.f,0.f,0.f};
#pragma unroll 1
            for (int s = 0; s < 8; ++s) {
                const int hoff = s * 32 + q * 8;
                short8 Bh = BF(&h0hi[bq][hoff]);
                short8 Bl = BF(&h0lo[bq][hoff]);
                const short* fs0 = fb0 + s * 512;
                MS1(Zi, 0) MS1(Zf, 1) MS1(Zg, 2) MS1(Zo, 3)
            }
            GATE0(0) GATE0(1) GATE0(2) GATE0(3)
        }
        if (w >= 2 && p >= 1) {         // layer 1
            floatx4 Yi = {0.f,0.f,0.f,0.f}, Yf = {0.f,0.f,0.f,0.f};
            floatx4 Yg = {0.f,0.f,0.f,0.f}, Yo = {0.f,0.f,0.f,0.f};
#pragma unroll 1
            for (int s = 0; s < 8; ++s) {
                const int hoff = s * 32 + q * 8;
                short8 Bh = BF(&h0hi[bq][hoff]);
                short8 Bl = BF(&h0lo[bq][hoff]);
                short8 Ch = BF(&h1hi[bq][hoff]);
                short8 Cl = BF(&h1lo[bq][hoff]);
                const short* fs1 = fb1 + s * 512;
                const short* fs2 = fb2 + s * 512;
                MS3(Yi, 0) MS3(Yf, 1) MS3(Yg, 2) MS3(Yo, 3)
            }
            float part = 0.0f;
            GATE1L(0) GATE1L(1) GATE1L(2) GATE1L(3)
            part += __shfl_xor(part, 16, 64);
            part += __shfl_xor(part, 32, 64);
            if (q == 0)                  // direct device-scope posc store
                stf_dev(poscw + j * 32 + (w - 2) * 16 + bq, part);
        }
        vmcnt0();                        // this wave's stores acked at coherence point
        if (lane == 0)                   // device-scope counter bump (executes at MALL)
            atomicAdd(cnt, 1u);
        {                                // per-wave spin: 1 poll lane, whole wave lockstep
            const u32 tgt = 32u * (u32)(p + 1);
            if (lane == 0) {
                int it = 0;
                while (ld32_poll_sys(cnt) < tgt) {
                    __builtin_amdgcn_s_sleep(1);
                    if (++it > 50000) break;     // finite-wrong, never hang
                }
            }
        }
        // ---- readback ISSUE immediately (overlaps barrier + other waves' tails)
        u32x4 va0, va1, va2, va3, vb0, vb1, vb2, vb3;
        float po[16];
        const u32x4* s4a = (const u32x4*)hx0w;
        const u32x4* s4b = (const u32x4*)hx1w;
        const bool doout = (p >= 1) && (j == 0) && (tid < 16);
        if (p < TT) {
            va0 = ld128_dev(s4a + tid);
            va1 = ld128_dev(s4a + tid + 256);
            va2 = ld128_dev(s4a + tid + 512);
            va3 = ld128_dev(s4a + tid + 768);
        }
        if (p >= 1) {
            vb0 = ld128_dev(s4b + tid);
            vb1 = ld128_dev(s4b + tid + 256);
            vb2 = ld128_dev(s4b + tid + 512);
            vb3 = ld128_dev(s4b + tid + 768);
        }
        if (doout) {
            const float* pp = poscw + tid;           // [jj][half][b=tid]
#pragma unroll
            for (int jj = 0; jj < 8; ++jj) {
                po[2 * jj]     = ldf_dev(pp + jj * 32);
                po[2 * jj + 1] = ldf_dev(pp + jj * 32 + 16);
            }
        }
        __syncthreads();                 // all waves done reading old LDS h planes
        vmcnt0();                        // readback loads complete
        if (p < TT) {
            KEEP(va0); KEEP(va1); KEEP(va2); KEEP(va3);
            UNPACK0(va0, tid); UNPACK0(va1, tid + 256);
            UNPACK0(va2, tid + 512); UNPACK0(va3, tid + 768);
        }
        if (p >= 1) {
            KEEP(vb0); KEEP(vb1); KEEP(vb2); KEEP(vb3);
            UNPACK1(vb0, tid); UNPACK1(vb1, tid + 256);
            UNPACK1(vb2, tid + 512); UNPACK1(vb3, tid + 768);
        }
        if (doout) {                     // assemble out[t = p-1]
#pragma unroll
            for (int jj = 0; jj < 16; ++jj) KEEP(po[jj]);
            float o = bho;
#pragma unroll
            for (int jj = 0; jj < 16; ++jj) o += po[jj];
            out[(bglo + tid) * TT + (p - 1)] = o;    // plain store: host-read after kernel end
        }
        __syncthreads();                 // LDS h planes ready for next phase
    }
}

extern "C" void kernel_launch(void* const* d_in, const int* in_sizes, int n_in,
                              void* d_out, int out_size, void* d_ws, size_t ws_size,
                              hipStream_t stream)
{
    const float* latent = (const float*)d_in[0];
    const float* W_lh   = (const float*)d_in[1];
    const float* b_lh   = (const float*)d_in[2];
    // d_in[3] = W_ih0: unused (layer-0 inputs are all-zero)
    const float* W_hh0  = (const float*)d_in[4];
    const float* b_ih0  = (const float*)d_in[5];
    const float* b_hh0  = (const float*)d_in[6];
    const float* W_ih1  = (const float*)d_in[7];
    const float* W_hh1  = (const float*)d_in[8];
    const float* b_ih1  = (const float*)d_in[9];
    const float* b_hh1  = (const float*)d_in[10];
    const float* W_ho   = (const float*)d_in[11];
    const float* b_ho   = (const float*)d_in[12];

    char* ws = (char*)d_ws;
    short* frag = (short*)ws;                     // 1,572,864 B
    u32*   hx0  = (u32*)(ws + 1572864);           //   524,288 B (2 parities)
    u32*   hx1  = (u32*)(ws + 2097152);           //   524,288 B
    float* posc = (float*)(ws + 2621440);         //    32,768 B (2 parities x 16g x 8j x 2 x 16)
    u32*   flg  = (u32*)(ws + 2654208);           //     2,048 B: 16 counters, 128B apart

    zero_flags<<<dim3(1), dim3(512), 0, stream>>>(flg);
    lstm_skew<<<dim3(128), dim3(256), 0, stream>>>(latent, W_lh, b_lh,
                                                   W_hh0, b_ih0, b_hh0,
                                                   W_ih1, W_hh1, b_ih1, b_hh1,
                                                   W_ho, b_ho,
                                                   frag, hx0, hx1, posc, flg,
                                                   (float*)d_out);
}

// Round 5
// 3527.169 us; speedup vs baseline: 1.3930x; 1.3930x over previous
//
#include <hip/hip_runtime.h>
#include <cstdint>

#define TT 512

typedef unsigned short u16;
typedef uint32_t u32;
typedef float  floatx4 __attribute__((ext_vector_type(4)));
typedef short  short8  __attribute__((ext_vector_type(8)));
typedef u32    u32x4   __attribute__((ext_vector_type(4)));

__device__ __forceinline__ float bf2f(u16 u) {
    union { u32 i; float f; } v; v.i = ((u32)u) << 16; return v.f;
}
__device__ __forceinline__ u16 f2bf(float f) {
    union { float f; u32 i; } v; v.f = f;
    u32 x = v.i;
    return (u16)((x + 0x7fffu + ((x >> 16) & 1u)) >> 16);  // RNE
}
__device__ __forceinline__ float sigm(float x)  { return 1.0f / (1.0f + __expf(-x)); }
__device__ __forceinline__ float tanh_(float x) { return 2.0f / (1.0f + __expf(-2.0f * x)) - 1.0f; }
#define BF(p) (*(const short8*)(p))

// ---- coherence recipe (r1-r4 measured):
// data stores: sc1 (agent). Write-through; r2 proved same-XCD consumers see
//   them coherently in the shared XCD L2 (512 phases bit-correct via sc0 reads).
// flags: single writer per EXCLUSIVE 128B line (r4: contended atomics = -45%),
//   stored sc1, polled sc0sc1 (authoritative at MALL; r2: L1-resident polls
//   without bypass never see updates).
// fast readback (XCC-handshake-verified same-XCD): buffer_inv sc0 (L1 inv,
//   leaves L2 + weight frags intact) then PLAIN loads -> shared-L2 latency.
// safe readback: sc1 loads (r3 behavior, 3378 us).
__device__ __forceinline__ void st32_dev(u32* p, u32 v) {
    asm volatile("global_store_dword %0, %1, off sc1" :: "v"(p), "v"(v) : "memory");
}
__device__ __forceinline__ void stf_dev(float* p, float v) {
    asm volatile("global_store_dword %0, %1, off sc1" :: "v"(p), "v"(v) : "memory");
}
__device__ __forceinline__ u32 ld32_poll_sys(const u32* p) {       // self-waiting (spin)
    u32 v;
    asm volatile("global_load_dword %0, %1, off sc0 sc1\n\ts_waitcnt vmcnt(0)"
                 : "=v"(v) : "v"(p) : "memory");
    return v;
}
template<bool FASTP> __device__ __forceinline__ u32x4 ld128_rb(const u32x4* p) {  // pipelined
    u32x4 v;
    if constexpr (FASTP)
        asm volatile("global_load_dwordx4 %0, %1, off" : "=v"(v) : "v"(p));
    else
        asm volatile("global_load_dwordx4 %0, %1, off sc1" : "=v"(v) : "v"(p));
    return v;
}
template<bool FASTP> __device__ __forceinline__ float ldf_rb(const float* p) {    // pipelined
    float v;
    if constexpr (FASTP)
        asm volatile("global_load_dword %0, %1, off" : "=v"(v) : "v"(p));
    else
        asm volatile("global_load_dword %0, %1, off sc1" : "=v"(v) : "v"(p));
    return v;
}
__device__ __forceinline__ void l1inv() { asm volatile("buffer_inv sc0" ::: "memory"); }
// always-system helpers (handshake; must work under any placement)
__device__ __forceinline__ void st_coh32(u32* p, u32 v) {
    asm volatile("global_store_dword %0, %1, off sc0 sc1" :: "v"(p), "v"(v) : "memory");
}
__device__ __forceinline__ u32 ld_coh32(const u32* p) {
    u32 v;
    asm volatile("global_load_dword %0, %1, off sc0 sc1\n\ts_waitcnt vmcnt(0)"
                 : "=v"(v) : "v"(p) : "memory");
    return v;
}
__device__ __forceinline__ void vmcnt0() { asm volatile("s_waitcnt vmcnt(0)" ::: "memory"); }
#define KEEP(x) asm volatile("" : "+v"(x))   // consume-after-wait fence (rule #18)

__global__ void zero_flags(u32* flg) {       // 4224 u32: 128 flag lines + xcc table
#pragma unroll
    for (int k = 0; k < 5; ++k) {
        const int idx = threadIdx.x + 1024 * k;
        if (idx < 4224)
            asm volatile("global_store_dword %0, %1, off sc0 sc1"
                         :: "v"(&flg[idx]), "v"(0u) : "memory");
    }
}

#define MFMA_(A_, B_, ACC) ACC = __builtin_amdgcn_mfma_f32_16x16x32_bf16(A_, B_, ACC, 0, 0, 0)
#define MS1(ACC, GATE_) { short8 A_ = BF(fs0 + (GATE_) * 4096); \
    MFMA_(A_, Bh, ACC); MFMA_(A_, Bl, ACC); }
#define MS3(ACC, GATE_) { short8 A1_ = BF(fs1 + (GATE_) * 4096); \
    MFMA_(A1_, Bh, ACC); MFMA_(A1_, Bl, ACC); \
    short8 A2_ = BF(fs2 + (GATE_) * 4096); \
    MFMA_(A2_, Ch, ACC); MFMA_(A2_, Cl, ACC); }

#define GATE0(R) { \
    const int d_ = dg16 + 4 * q + (R); \
    float zi_ = Zi[R] + b0s[0][d_], zf_ = Zf[R] + b0s[1][d_]; \
    float zg_ = Zg[R] + b0s[2][d_], zo_ = Zo[R] + b0s[3][d_]; \
    float c_  = sigm(zf_) * c0v[R] + sigm(zi_) * tanh_(zg_); c0v[R] = c_; \
    float hv_ = sigm(zo_) * tanh_(c_); \
    u16 hi_ = f2bf(hv_); u16 lo_ = f2bf(hv_ - bf2f(hi_)); \
    st32_dev(&hx0w[d_ * 16 + bq], ((u32)hi_ << 16) | (u32)lo_); }
#define GATE1L(R) { \
    const int d_ = dg16 + 4 * q + (R); \
    float zi_ = Yi[R] + b1s[0][d_], zf_ = Yf[R] + b1s[1][d_]; \
    float zg_ = Yg[R] + b1s[2][d_], zo_ = Yo[R] + b1s[3][d_]; \
    float c_  = sigm(zf_) * c1v[R] + sigm(zi_) * tanh_(zg_); c1v[R] = c_; \
    float hv_ = sigm(zo_) * tanh_(c_); \
    u16 hi_ = f2bf(hv_); u16 lo_ = f2bf(hv_ - bf2f(hi_)); \
    st32_dev(&hx1w[d_ * 16 + bq], ((u32)hi_ << 16) | (u32)lo_); \
    part += hv_ * who_s[d_]; }

#define UNPACK0(v, i4) { const int d_ = (i4) >> 2, bb_ = ((i4) & 3) * 4; \
    h0hi[bb_ + 0][d_] = (short)((v)[0] >> 16); h0lo[bb_ + 0][d_] = (short)((v)[0] & 0xFFFFu); \
    h0hi[bb_ + 1][d_] = (short)((v)[1] >> 16); h0lo[bb_ + 1][d_] = (short)((v)[1] & 0xFFFFu); \
    h0hi[bb_ + 2][d_] = (short)((v)[2] >> 16); h0lo[bb_ + 2][d_] = (short)((v)[2] & 0xFFFFu); \
    h0hi[bb_ + 3][d_] = (short)((v)[3] >> 16); h0lo[bb_ + 3][d_] = (short)((v)[3] & 0xFFFFu); }
#define UNPACK1(v, i4) { const int d_ = (i4) >> 2, bb_ = ((i4) & 3) * 4; \
    h1hi[bb_ + 0][d_] = (short)((v)[0] >> 16); h1lo[bb_ + 0][d_] = (short)((v)[0] & 0xFFFFu); \
    h1hi[bb_ + 1][d_] = (short)((v)[1] >> 16); h1lo[bb_ + 1][d_] = (short)((v)[1] & 0xFFFFu); \
    h1hi[bb_ + 2][d_] = (short)((v)[2] >> 16); h1lo[bb_ + 2][d_] = (short)((v)[2] & 0xFFFFu); \
    h1hi[bb_ + 3][d_] = (short)((v)[3] >> 16); h1lo[bb_ + 3][d_] = (short)((v)[3] & 0xFFFFu); }

// Phase structure (2 barriers):
//   compute (sc1 hx/posc stores inline) -> per-wave vmcnt(0) -> BAR
//   -> tid0 flag store (exclusive 128B line) -> ALL-wave parallel spin
//   (lanes 0-7 poll 8 exclusive lines, ballot exit) -> per-wave readback issue
//   (FASTP: buffer_inv sc0 + plain loads from shared XCD L2)
//   -> vmcnt(0) -> unpack -> out -> BAR.
template<bool FASTP>
__device__ __forceinline__ void phase_loop(
    short (*h0hi)[264], short (*h0lo)[264], short (*h1hi)[264], short (*h1lo)[264],
    float (*b0s)[256], float (*b1s)[256], float* who_s,
    const short* fb0, const short* fb1, const short* fb2,
    u32* hx0, u32* hx1, float* posc, u32* flg, float* out,
    int tid, int w, int lane, int bq, int q, int g, int j, int bglo, float bho)
{
    const int dg16 = (2 * j + (w & 1)) * 16;
    u32* myflag = flg + (g * 8 + j) * 32;        // exclusive 128B line
    u32* gflags = flg + g * 8 * 32;
    float c0v[4] = {0.f, 0.f, 0.f, 0.f}, c1v[4] = {0.f, 0.f, 0.f, 0.f};

    for (int p = 0; p <= TT; ++p) {
        const int pb = p & 1;
        u32* hx0w = hx0 + pb * 65536 + g * 4096;
        u32* hx1w = hx1 + pb * 65536 + g * 4096;
        float* poscw = posc + pb * 4096 + g * 256;   // [j][half][16]

        if (w < 2 && p < TT) {          // layer 0
            floatx4 Zi = {0.f,0.f,0.f,0.f}, Zf = {0.f,0.f,0.f,0.f};
            floatx4 Zg = {0.f,0.f,0.f,0.f}, Zo = {0.f,0.f,0.f,0.f};
#pragma unroll 1
            for (int s = 0; s < 8; ++s) {
                const int hoff = s * 32 + q * 8;
                short8 Bh = BF(&h0hi[bq][hoff]);
                short8 Bl = BF(&h0lo[bq][hoff]);
                const short* fs0 = fb0 + s * 512;
                MS1(Zi, 0) MS1(Zf, 1) MS1(Zg, 2) MS1(Zo, 3)
            }
            GATE0(0) GATE0(1) GATE0(2) GATE0(3)
        }
        if (w >= 2 && p >= 1) {         // layer 1
            floatx4 Yi = {0.f,0.f,0.f,0.f}, Yf = {0.f,0.f,0.f,0.f};
            floatx4 Yg = {0.f,0.f,0.f,0.f}, Yo = {0.f,0.f,0.f,0.f};
#pragma unroll 1
            for (int s = 0; s < 8; ++s) {
                const int hoff = s * 32 + q * 8;
                short8 Bh = BF(&h0hi[bq][hoff]);
                short8 Bl = BF(&h0lo[bq][hoff]);
                short8 Ch = BF(&h1hi[bq][hoff]);
                short8 Cl = BF(&h1lo[bq][hoff]);
                const short* fs1 = fb1 + s * 512;
                const short* fs2 = fb2 + s * 512;
                MS3(Yi, 0) MS3(Yf, 1) MS3(Yg, 2) MS3(Yo, 3)
            }
            float part = 0.0f;
            GATE1L(0) GATE1L(1) GATE1L(2) GATE1L(3)
            part += __shfl_xor(part, 16, 64);
            part += __shfl_xor(part, 32, 64);
            if (q == 0)
                stf_dev(poscw + j * 32 + (w - 2) * 16 + bq, part);
        }
        vmcnt0();                        // this wave's stores acked at coherence point
        __syncthreads();                 // all compute + acks done; LDS planes free
        if (tid == 0)
            st32_dev(myflag, (u32)(p + 1));
        {                                // all-wave parallel spin, ballot exit
            const u32 tgt = (u32)(p + 1);
            int it = 0;
            while (true) {
                u32 f = tgt;
                if (lane < 8) f = ld32_poll_sys(gflags + lane * 32);
                if (__ballot(f >= tgt) == 0xFFFFFFFFFFFFFFFFull) break;
                __builtin_amdgcn_s_sleep(1);
                if (++it > 50000) break; // finite-wrong, never hang
            }
        }
        if constexpr (FASTP) l1inv();    // L1-only inv; L2 (weights, hx) untouched
        // ---- per-wave pipelined readback: h0(p+1), h1(p), posc(p)
        u32x4 va0, va1, va2, va3, vb0, vb1, vb2, vb3;
        float po[16];
        const u32x4* s4a = (const u32x4*)hx0w;
        const u32x4* s4b = (const u32x4*)hx1w;
        const bool doout = (p >= 1) && (j == 0) && (tid < 16);
        if (p < TT) {
            va0 = ld128_rb<FASTP>(s4a + tid);
            va1 = ld128_rb<FASTP>(s4a + tid + 256);
            va2 = ld128_rb<FASTP>(s4a + tid + 512);
            va3 = ld128_rb<FASTP>(s4a + tid + 768);
        }
        if (p >= 1) {
            vb0 = ld128_rb<FASTP>(s4b + tid);
            vb1 = ld128_rb<FASTP>(s4b + tid + 256);
            vb2 = ld128_rb<FASTP>(s4b + tid + 512);
            vb3 = ld128_rb<FASTP>(s4b + tid + 768);
        }
        if (doout) {
            const float* pp = poscw + tid;
#pragma unroll
            for (int jj = 0; jj < 8; ++jj) {
                po[2 * jj]     = ldf_rb<FASTP>(pp + jj * 32);
                po[2 * jj + 1] = ldf_rb<FASTP>(pp + jj * 32 + 16);
            }
        }
        vmcnt0();                        // readback loads complete
        if (p < TT) {
            KEEP(va0); KEEP(va1); KEEP(va2); KEEP(va3);
            UNPACK0(va0, tid); UNPACK0(va1, tid + 256);
            UNPACK0(va2, tid + 512); UNPACK0(va3, tid + 768);
        }
        if (p >= 1) {
            KEEP(vb0); KEEP(vb1); KEEP(vb2); KEEP(vb3);
            UNPACK1(vb0, tid); UNPACK1(vb1, tid + 256);
            UNPACK1(vb2, tid + 512); UNPACK1(vb3, tid + 768);
        }
        if (doout) {
#pragma unroll
            for (int jj = 0; jj < 16; ++jj) KEEP(po[jj]);
            float o = bho;
#pragma unroll
            for (int jj = 0; jj < 16; ++jj) o += po[jj];
            out[(bglo + tid) * TT + (p - 1)] = o;
        }
        __syncthreads();                 // LDS h planes ready for next phase
    }
}

// 128 blocks = 16 groups x 8 dim-slices. g=bid&15 puts a group's 8 slices at
// the same bid%8 -> same XCD under round-robin dispatch; XCC_ID handshake
// verifies before engaging plain-load (L2-latency) readback.
__launch_bounds__(256, 2)
__global__ void lstm_skew(const float* __restrict__ latent, const float* __restrict__ W_lh,
                          const float* __restrict__ b_lh,
                          const float* __restrict__ W_hh0,
                          const float* __restrict__ b_ih0, const float* __restrict__ b_hh0,
                          const float* __restrict__ W_ih1, const float* __restrict__ W_hh1,
                          const float* __restrict__ b_ih1, const float* __restrict__ b_hh1,
                          const float* __restrict__ W_ho,  const float* __restrict__ b_ho,
                          short* __restrict__ frag, u32* __restrict__ hx0, u32* __restrict__ hx1,
                          float* __restrict__ posc, u32* __restrict__ flg,
                          float* __restrict__ out)
{
    __shared__ __align__(16) short h0hi[16][264], h0lo[16][264];
    __shared__ __align__(16) short h1hi[16][264], h1lo[16][264];
    __shared__ float b0s[4][256], b1s[4][256];
    __shared__ float who_s[256];
    __shared__ int fast_s;

    const int tid  = threadIdx.x;      // 256 threads, 4 waves
    const int w    = tid >> 6;
    const int lane = tid & 63;
    const int bq   = lane & 15;
    const int q    = lane >> 4;
    const int bid  = blockIdx.x;
    const int g    = bid & 15;         // batch group
    const int j    = bid >> 4;         // dim slice 0..7
    const int bglo = g * 16;
    u32* xcct = flg + 4096;            // xcc handshake table

    // ---- stage this slice's weight fragments (identical bytes across groups: benign race)
    for (int i = tid; i < 12288; i += 256) {
        const int l8 = i & 63, s8 = (i >> 6) & 7, gate8 = (i >> 9) & 3;
        const int dgl = (i >> 11) & 1, G = i >> 12;
        const int dgw = 2 * j + dgl;
        const float* W = (G == 0) ? W_hh0 : (G == 1) ? W_ih1 : W_hh1;
        const float* src = W + (gate8 * 256 + dgw * 16 + (l8 & 15)) * 256
                             + s8 * 32 + (l8 >> 4) * 8;
        short8 v;
#pragma unroll
        for (int jj = 0; jj < 8; ++jj) v[jj] = (short)f2bf(src[jj]);
        *(short8*)(frag + (size_t)(l8 * 8 + s8 * 512 + gate8 * 4096 + dgw * 16384 + G * 262144)) = v;
    }
    for (int i = tid; i < 1024; i += 256) {
        b0s[i >> 8][i & 255] = b_ih0[i] + b_hh0[i];
        b1s[i >> 8][i & 255] = b_ih1[i] + b_hh1[i];
    }
    if (tid < 256) who_s[tid] = W_ho[tid];

    // h_init = latent @ W_lh.T + b_lh (fp32), split hi/lo
    {
        const int b = tid >> 4, d0 = (tid & 15) * 16;
        const float* lr = latent + (bglo + b) * 128;
#pragma unroll
        for (int jj = 0; jj < 16; ++jj) {
            const int d = d0 + jj;
            const float* wr = W_lh + d * 128;
            float acc = b_lh[d];
            for (int c = 0; c < 128; c += 4) {
                float4 lv = *(const float4*)(lr + c);
                float4 wv = *(const float4*)(wr + c);
                acc += lv.x * wv.x + lv.y * wv.y + lv.z * wv.z + lv.w * wv.w;
            }
            u16 hi = f2bf(acc), lo = f2bf(acc - bf2f(hi));
            h0hi[b][d] = (short)hi; h0lo[b][d] = (short)lo;
            h1hi[b][d] = (short)hi; h1lo[b][d] = (short)lo;
        }
    }

    // ---- XCC placement handshake (system scope, one-time)
    u32 myxcc;
    asm volatile("s_getreg_b32 %0, hwreg(HW_REG_XCC_ID)" : "=s"(myxcc));
    myxcc &= 0xFFu;
    if (tid == 0) {
        vmcnt0();
        st_coh32(xcct + bid, myxcc | 0x100u);
    }
    u32 part_ok = 0;
    if (tid < 8) {
        const u32* pp = xcct + g + 16 * tid;     // partner block (g, jj=tid)
        u32 v = 0; int it = 0;
        do {
            v = ld_coh32(pp);
            if (++it > 200000) break;
        } while (!(v & 0x100u));
        part_ok = ((v & 0x100u) && ((v & 0xFFu) == myxcc)) ? 1u : 0u;
    }
    unsigned long long bal = __ballot(part_ok != 0);
    if (tid == 0) fast_s = ((bal & 0xFFull) == 0xFFull) ? 1 : 0;
    __syncthreads();                     // fast_s + LDS h planes ready

    const int dgw   = 2 * j + (w & 1);
    const short* fb0 = frag + dgw * 16384 + (size_t)lane * 8;
    const short* fb1 = frag + 262144 + dgw * 16384 + (size_t)lane * 8;
    const short* fb2 = fb1 + 262144;
    const float bho = b_ho[0];

    if (fast_s)
        phase_loop<true>(h0hi, h0lo, h1hi, h1lo, b0s, b1s, who_s,
                         fb0, fb1, fb2, hx0, hx1, posc, flg, out,
                         tid, w, lane, bq, q, g, j, bglo, bho);
    else
        phase_loop<false>(h0hi, h0lo, h1hi, h1lo, b0s, b1s, who_s,
                          fb0, fb1, fb2, hx0, hx1, posc, flg, out,
                          tid, w, lane, bq, q, g, j, bglo, bho);
}

extern "C" void kernel_launch(void* const* d_in, const int* in_sizes, int n_in,
                              void* d_out, int out_size, void* d_ws, size_t ws_size,
                              hipStream_t stream)
{
    const float* latent = (const float*)d_in[0];
    const float* W_lh   = (const float*)d_in[1];
    const float* b_lh   = (const float*)d_in[2];
    // d_in[3] = W_ih0: unused (layer-0 inputs are all-zero)
    const float* W_hh0  = (const float*)d_in[4];
    const float* b_ih0  = (const float*)d_in[5];
    const float* b_hh0  = (const float*)d_in[6];
    const float* W_ih1  = (const float*)d_in[7];
    const float* W_hh1  = (const float*)d_in[8];
    const float* b_ih1  = (const float*)d_in[9];
    const float* b_hh1  = (const float*)d_in[10];
    const float* W_ho   = (const float*)d_in[11];
    const float* b_ho   = (const float*)d_in[12];

    char* ws = (char*)d_ws;
    short* frag = (short*)ws;                     // 1,572,864 B
    u32*   hx0  = (u32*)(ws + 1572864);           //   524,288 B (2 parities)
    u32*   hx1  = (u32*)(ws + 2097152);           //   524,288 B
    float* posc = (float*)(ws + 2621440);         //    32,768 B
    u32*   flg  = (u32*)(ws + 2654208);           //    16,896 B: 128 x 128B flag lines + xcc[128]

    zero_flags<<<dim3(1), dim3(1024), 0, stream>>>(flg);
    lstm_skew<<<dim3(128), dim3(256), 0, stream>>>(latent, W_lh, b_lh,
                                                   W_hh0, b_ih0, b_hh0,
                                                   W_ih1, W_hh1, b_ih1, b_hh1,
                                                   W_ho, b_ho,
                                                   frag, hx0, hx1, posc, flg,
                                                   (float*)d_out);
}

// Round 7
// 3458.378 us; speedup vs baseline: 1.4207x; 1.0199x over previous
//
#include <hip/hip_runtime.h>
#include <cstdint>

#define TT 512

typedef unsigned short u16;
typedef uint32_t u32;
typedef float    floatx4 __attribute__((ext_vector_type(4)));
typedef _Float16 f16x8   __attribute__((ext_vector_type(8)));
typedef short    short8  __attribute__((ext_vector_type(8)));
typedef u32      u32x4   __attribute__((ext_vector_type(4)));
typedef u32      u32x2   __attribute__((ext_vector_type(2)));

__device__ __forceinline__ float sigm(float x)  { return 1.0f / (1.0f + __expf(-x)); }
__device__ __forceinline__ float tanh_(float x) { return 2.0f / (1.0f + __expf(-2.0f * x)) - 1.0f; }
__device__ __forceinline__ u16 f2h(float f) {           // f32 -> fp16 bits (RNE)
    union { _Float16 h; u16 u; } v; v.h = (_Float16)f; return v.u;
}
#define F16V(p) (*(const f16x8*)(const void*)(p))

// ---- agent-scope (sc1) accesses: coherent at the MALL. r1-r5 measured: the
// per-trip scope barely matters; the TRIP COUNT does. Protocol: self-announcing
// data [stamp16|value16], fire-and-forget stores, consumer retry loop.
// No vmcnt ack, no flag, no poll -> 1 trip/phase, not 4.
// r6 failed NOT from this protocol but from a posc readback addressing bug
// (tid*4 instead of tid*8 u32x4 stride) -- fixed this round.
__device__ __forceinline__ void st32_dev(u32* p, u32 v) {
    asm volatile("global_store_dword %0, %1, off sc1" :: "v"(p), "v"(v) : "memory");
}
__device__ __forceinline__ void st64_dev(u32* p, u32 lo, u32 hi) {  // single dwordx2 packet
    u32x2 d; d[0] = lo; d[1] = hi;
    asm volatile("global_store_dwordx2 %0, %1, off sc1" :: "v"(p), "v"(d) : "memory");
}
__device__ __forceinline__ u32x4 ld128_dev(const u32x4* p) {        // pipelined: no wait
    u32x4 v;
    asm volatile("global_load_dwordx4 %0, %1, off sc1" : "=v"(v) : "v"(p));
    return v;
}
__device__ __forceinline__ void vmcnt0() { asm volatile("s_waitcnt vmcnt(0)" ::: "memory"); }
#define KEEP(x) asm volatile("" : "+v"(x))   // consume-after-wait fence (rule #18)

// zero stamps each launch: stale stamps from a prior run are in 1..513 and
// would false-accept. Covers hx0+hx1+posc (contiguous, 69632 dwordx4).
__global__ void zero_ws(u32* base, int n4) {
    u32x4 z = {0u, 0u, 0u, 0u};
    for (int i = blockIdx.x * blockDim.x + threadIdx.x; i < n4; i += gridDim.x * blockDim.x)
        asm volatile("global_store_dwordx4 %0, %1, off sc1"
                     :: "v"(((u32x4*)base) + i), "v"(z) : "memory");
}

// f16 MFMA: h in (-1,1), |W| <= 0.0625 -> fp16's 11-bit mantissa BEATS the old
// single-bf16 weights (2^-12 vs 2^-9 abs) while halving MFMA count (no hi/lo).
#define MFMA_(A_, B_, ACC) ACC = __builtin_amdgcn_mfma_f32_16x16x32_f16(A_, B_, ACC, 0, 0, 0)
#define MS1(ACC, GATE_) { f16x8 A_ = F16V(fs0 + (GATE_) * 4096); MFMA_(A_, Bh, ACC); }
#define MS3(ACC, GATE_) { f16x8 A1_ = F16V(fs1 + (GATE_) * 4096); MFMA_(A1_, Bh, ACC); \
    f16x8 A2_ = F16V(fs2 + (GATE_) * 4096); MFMA_(A2_, Ch, ACC); }

// gates: update c, publish [stamp16|f16] via fire-and-forget sc1 store
#define GATE0(R) { \
    const int d_ = dg16 + 4 * q + (R); \
    float zi_ = Zi[R] + b0s[0][d_], zf_ = Zf[R] + b0s[1][d_]; \
    float zg_ = Zg[R] + b0s[2][d_], zo_ = Zo[R] + b0s[3][d_]; \
    float c_  = sigm(zf_) * c0v[R] + sigm(zi_) * tanh_(zg_); c0v[R] = c_; \
    float hv_ = sigm(zo_) * tanh_(c_); \
    st32_dev(&hx0w[d_ * 16 + bq], tgthi | (u32)f2h(hv_)); }
#define GATE1L(R) { \
    const int d_ = dg16 + 4 * q + (R); \
    float zi_ = Yi[R] + b1s[0][d_], zf_ = Yf[R] + b1s[1][d_]; \
    float zg_ = Yg[R] + b1s[2][d_], zo_ = Yo[R] + b1s[3][d_]; \
    float c_  = sigm(zf_) * c1v[R] + sigm(zi_) * tanh_(zg_); c1v[R] = c_; \
    float hv_ = sigm(zo_) * tanh_(c_); \
    st32_dev(&hx1w[d_ * 16 + bq], tgthi | (u32)f2h(hv_)); \
    part += hv_ * who_s[d_]; }

#define UNPACK0(v, i4) { const int d_ = (i4) >> 2, bb_ = ((i4) & 3) * 4; \
    h0f[bb_ + 0][d_] = (u16)((v)[0] & 0xFFFFu); \
    h0f[bb_ + 1][d_] = (u16)((v)[1] & 0xFFFFu); \
    h0f[bb_ + 2][d_] = (u16)((v)[2] & 0xFFFFu); \
    h0f[bb_ + 3][d_] = (u16)((v)[3] & 0xFFFFu); }
#define UNPACK1(v, i4) { const int d_ = (i4) >> 2, bb_ = ((i4) & 3) * 4; \
    h1f[bb_ + 0][d_] = (u16)((v)[0] & 0xFFFFu); \
    h1f[bb_ + 1][d_] = (u16)((v)[1] & 0xFFFFu); \
    h1f[bb_ + 2][d_] = (u16)((v)[2] & 0xFFFFu); \
    h1f[bb_ + 3][d_] = (u16)((v)[3] & 0xFFFFu); }
#define STALE4(v) (((v)[0] ^ tgthi) | ((v)[1] ^ tgthi) | ((v)[2] ^ tgthi) | ((v)[3] ^ tgthi))

// 128 blocks = 16 groups x 8 dim-slices. Phase:
//   compute (stamped sc1 stores inline) -> ISSUE readback attempt-1 -> BAR
//   -> {vmcnt; stamp-check; ballot; reissue}-loop -> unpack -> out -> BAR.
// Skew safety: block at phase p+2 implies all blocks passed phase-p readback,
// so parity-buffer overwrite (period 2) can't race readers (max skew 1).
__launch_bounds__(256, 1)
__global__ void lstm_skew(const float* __restrict__ latent, const float* __restrict__ W_lh,
                          const float* __restrict__ b_lh,
                          const float* __restrict__ W_hh0,
                          const float* __restrict__ b_ih0, const float* __restrict__ b_hh0,
                          const float* __restrict__ W_ih1, const float* __restrict__ W_hh1,
                          const float* __restrict__ b_ih1, const float* __restrict__ b_hh1,
                          const float* __restrict__ W_ho,  const float* __restrict__ b_ho,
                          short* __restrict__ frag, u32* __restrict__ hx0, u32* __restrict__ hx1,
                          u32* __restrict__ posc, float* __restrict__ out)
{
    __shared__ __align__(16) u16 h0f[16][264];   // h0(p), fp16, full 256 dims
    __shared__ __align__(16) u16 h1f[16][264];   // h1(p-1)
    __shared__ float b0s[4][256], b1s[4][256];
    __shared__ float who_s[256];

    const int tid  = threadIdx.x;      // 256 threads, 4 waves
    const int w    = tid >> 6;
    const int lane = tid & 63;
    const int bq   = lane & 15;
    const int q    = lane >> 4;
    const int g    = blockIdx.x & 15;  // batch group
    const int j    = blockIdx.x >> 4;  // dim slice 0..7
    const int bglo = g * 16;

    // ---- stage this slice's weight fragments as fp16 (benign cross-group race)
    for (int i = tid; i < 12288; i += 256) {
        const int l8 = i & 63, s8 = (i >> 6) & 7, gate8 = (i >> 9) & 3;
        const int dgl = (i >> 11) & 1, G = i >> 12;
        const int dgw = 2 * j + dgl;
        const float* W = (G == 0) ? W_hh0 : (G == 1) ? W_ih1 : W_hh1;
        const float* src = W + (gate8 * 256 + dgw * 16 + (l8 & 15)) * 256
                             + s8 * 32 + (l8 >> 4) * 8;
        short8 v;
#pragma unroll
        for (int jj = 0; jj < 8; ++jj) v[jj] = (short)f2h(src[jj]);
        *(short8*)(frag + (size_t)(l8 * 8 + s8 * 512 + gate8 * 4096 + dgw * 16384 + G * 262144)) = v;
    }
    for (int i = tid; i < 1024; i += 256) {
        b0s[i >> 8][i & 255] = b_ih0[i] + b_hh0[i];
        b1s[i >> 8][i & 255] = b_ih1[i] + b_hh1[i];
    }
    if (tid < 256) who_s[tid] = W_ho[tid];

    // h_init = latent @ W_lh.T + b_lh (fp32), rounded to fp16
    {
        const int b = tid >> 4, d0 = (tid & 15) * 16;
        const float* lr = latent + (bglo + b) * 128;
#pragma unroll
        for (int jj = 0; jj < 16; ++jj) {
            const int d = d0 + jj;
            const float* wr = W_lh + d * 128;
            float acc = b_lh[d];
            for (int c = 0; c < 128; c += 4) {
                float4 lv = *(const float4*)(lr + c);
                float4 wv = *(const float4*)(wr + c);
                acc += lv.x * wv.x + lv.y * wv.y + lv.z * wv.z + lv.w * wv.w;
            }
            u16 hb = f2h(acc);
            h0f[b][d] = hb; h1f[b][d] = hb;
        }
    }
    __syncthreads();

    // wave roles: w0,w1 = layer 0 (dim-groups 2j, 2j+1); w2,w3 = layer 1
    const int dgw   = 2 * j + (w & 1);
    const int dg16  = dgw * 16;
    const short* fb0 = frag + dgw * 16384 + (size_t)lane * 8;
    const short* fb1 = frag + 262144 + dgw * 16384 + (size_t)lane * 8;
    const short* fb2 = fb1 + 262144;
    float c0v[4] = {0.f, 0.f, 0.f, 0.f}, c1v[4] = {0.f, 0.f, 0.f, 0.f};
    const float bho = b_ho[0];

    for (int p = 0; p <= TT; ++p) {
        const int pb = p & 1;
        u32* hx0w = hx0 + pb * 65536 + g * 4096;
        u32* hx1w = hx1 + pb * 65536 + g * 4096;
        u32* poscw = posc + (pb * 16 + g) * 512;     // u32x2 entries [b*16 + j*2 + half]
        const u32 tgthi = (u32)(p + 1) << 16;
        const u32 tgt32 = (u32)(p + 1);

        if (w < 2 && p < TT) {          // layer 0
            floatx4 Zi = {0.f,0.f,0.f,0.f}, Zf = {0.f,0.f,0.f,0.f};
            floatx4 Zg = {0.f,0.f,0.f,0.f}, Zo = {0.f,0.f,0.f,0.f};
#pragma unroll 1
            for (int s = 0; s < 8; ++s) {
                const int hoff = s * 32 + q * 8;
                f16x8 Bh = F16V(&h0f[bq][hoff]);
                const short* fs0 = fb0 + s * 512;
                MS1(Zi, 0) MS1(Zf, 1) MS1(Zg, 2) MS1(Zo, 3)
            }
            GATE0(0) GATE0(1) GATE0(2) GATE0(3)
        }
        if (w >= 2 && p >= 1) {         // layer 1
            floatx4 Yi = {0.f,0.f,0.f,0.f}, Yf = {0.f,0.f,0.f,0.f};
            floatx4 Yg = {0.f,0.f,0.f,0.f}, Yo = {0.f,0.f,0.f,0.f};
#pragma unroll 1
            for (int s = 0; s < 8; ++s) {
                const int hoff = s * 32 + q * 8;
                f16x8 Bh = F16V(&h0f[bq][hoff]);
                f16x8 Ch = F16V(&h1f[bq][hoff]);
                const short* fs1 = fb1 + s * 512;
                const short* fs2 = fb2 + s * 512;
                MS3(Yi, 0) MS3(Yf, 1) MS3(Yg, 2) MS3(Yo, 3)
            }
            float part = 0.0f;
            GATE1L(0) GATE1L(1) GATE1L(2) GATE1L(3)
            part += __shfl_xor(part, 16, 64);
            part += __shfl_xor(part, 32, 64);
            if (q == 0)                  // [f32|stamp32] in ONE dwordx2 packet
                st64_dev(poscw + (bq * 16 + j * 2 + (w - 2)) * 2,
                         __float_as_uint(part), tgt32);
        }

        // ---- readback: attempt-1 issued BEFORE the barrier (latency hides under it)
        u32x4 va0, va1, va2, va3, vb0, vb1, vb2, vb3;
        u32x4 po0, po1, po2, po3, po4, po5, po6, po7;
        const u32x4* s4a = (const u32x4*)hx0w;
        const u32x4* s4b = (const u32x4*)hx1w;
        // batch b=tid owns words [b*32, b*32+32) = u32x4 [b*8, b*8+8)  (r6 bug: was tid*4)
        const u32x4* s4p = (const u32x4*)(poscw) + tid * 8;
        const bool doout = (p >= 1) && (j == 0) && (tid < 16);
#define ISSUE() do { \
        if (p < TT) { \
            va0 = ld128_dev(s4a + tid);       va1 = ld128_dev(s4a + tid + 256); \
            va2 = ld128_dev(s4a + tid + 512); va3 = ld128_dev(s4a + tid + 768); } \
        if (p >= 1) { \
            vb0 = ld128_dev(s4b + tid);       vb1 = ld128_dev(s4b + tid + 256); \
            vb2 = ld128_dev(s4b + tid + 512); vb3 = ld128_dev(s4b + tid + 768); } \
        if (doout) { \
            po0 = ld128_dev(s4p);     po1 = ld128_dev(s4p + 1); \
            po2 = ld128_dev(s4p + 2); po3 = ld128_dev(s4p + 3); \
            po4 = ld128_dev(s4p + 4); po5 = ld128_dev(s4p + 5); \
            po6 = ld128_dev(s4p + 6); po7 = ld128_dev(s4p + 7); } \
    } while (0)
        ISSUE();
        __syncthreads();                 // all waves done reading LDS planes
        int it = 0;
        while (true) {
            vmcnt0();
            u32 sh = 0, sf = 0;
            if (p < TT) {
                KEEP(va0); KEEP(va1); KEEP(va2); KEEP(va3);
                sh |= STALE4(va0) | STALE4(va1) | STALE4(va2) | STALE4(va3);
            }
            if (p >= 1) {
                KEEP(vb0); KEEP(vb1); KEEP(vb2); KEEP(vb3);
                sh |= STALE4(vb0) | STALE4(vb1) | STALE4(vb2) | STALE4(vb3);
            }
            if (doout) {
                KEEP(po0); KEEP(po1); KEEP(po2); KEEP(po3);
                KEEP(po4); KEEP(po5); KEEP(po6); KEEP(po7);
                sf |= (po0[1] ^ tgt32) | (po0[3] ^ tgt32) | (po1[1] ^ tgt32) | (po1[3] ^ tgt32)
                    | (po2[1] ^ tgt32) | (po2[3] ^ tgt32) | (po3[1] ^ tgt32) | (po3[3] ^ tgt32)
                    | (po4[1] ^ tgt32) | (po4[3] ^ tgt32) | (po5[1] ^ tgt32) | (po5[3] ^ tgt32)
                    | (po6[1] ^ tgt32) | (po6[3] ^ tgt32) | (po7[1] ^ tgt32) | (po7[3] ^ tgt32);
            }
            const bool ok = ((sh & 0xFFFF0000u) == 0u) && (sf == 0u);
            if (__ballot(ok) == 0xFFFFFFFFFFFFFFFFull) break;
            if (++it > 10000) break;     // finite-wrong, never hang
            ISSUE();
        }
#undef ISSUE
        // ---- unpack accepted data into LDS planes
        if (p < TT) {
            UNPACK0(va0, tid); UNPACK0(va1, tid + 256);
            UNPACK0(va2, tid + 512); UNPACK0(va3, tid + 768);
        }
        if (p >= 1) {
            UNPACK1(vb0, tid); UNPACK1(vb1, tid + 256);
            UNPACK1(vb2, tid + 512); UNPACK1(vb3, tid + 768);
        }
        if (doout) {                     // assemble out[t = p-1]
            float o = bho;
            o += __uint_as_float(po0[0]) + __uint_as_float(po0[2]);
            o += __uint_as_float(po1[0]) + __uint_as_float(po1[2]);
            o += __uint_as_float(po2[0]) + __uint_as_float(po2[2]);
            o += __uint_as_float(po3[0]) + __uint_as_float(po3[2]);
            o += __uint_as_float(po4[0]) + __uint_as_float(po4[2]);
            o += __uint_as_float(po5[0]) + __uint_as_float(po5[2]);
            o += __uint_as_float(po6[0]) + __uint_as_float(po6[2]);
            o += __uint_as_float(po7[0]) + __uint_as_float(po7[2]);
            out[(bglo + tid) * TT + (p - 1)] = o;
        }
        __syncthreads();                 // LDS h planes ready for next phase
    }
}

extern "C" void kernel_launch(void* const* d_in, const int* in_sizes, int n_in,
                              void* d_out, int out_size, void* d_ws, size_t ws_size,
                              hipStream_t stream)
{
    const float* latent = (const float*)d_in[0];
    const float* W_lh   = (const float*)d_in[1];
    const float* b_lh   = (const float*)d_in[2];
    // d_in[3] = W_ih0: unused (layer-0 inputs are all-zero)
    const float* W_hh0  = (const float*)d_in[4];
    const float* b_ih0  = (const float*)d_in[5];
    const float* b_hh0  = (const float*)d_in[6];
    const float* W_ih1  = (const float*)d_in[7];
    const float* W_hh1  = (const float*)d_in[8];
    const float* b_ih1  = (const float*)d_in[9];
    const float* b_hh1  = (const float*)d_in[10];
    const float* W_ho   = (const float*)d_in[11];
    const float* b_ho   = (const float*)d_in[12];

    char* ws = (char*)d_ws;
    short* frag = (short*)ws;                     // 1,572,864 B (fp16 weights)
    u32*   hx0  = (u32*)(ws + 1572864);           //   524,288 B (2 parities, [stamp16|f16])
    u32*   hx1  = (u32*)(ws + 2097152);           //   524,288 B
    u32*   posc = (u32*)(ws + 2621440);           //    65,536 B (2 par x 16g x 256 x [f32|stamp32])
    // total 2,686,976 B

    // zero all stamps (hx0+hx1+posc contiguous = 1,114,112 B = 69,632 dwordx4)
    zero_ws<<<dim3(128), dim3(256), 0, stream>>>(hx0, 69632);
    lstm_skew<<<dim3(128), dim3(256), 0, stream>>>(latent, W_lh, b_lh,
                                                   W_hh0, b_ih0, b_hh0,
                                                   W_ih1, W_hh1, b_ih1, b_hh1,
                                                   W_ho, b_ho,
                                                   frag, hx0, hx1, posc,
                                                   (float*)d_out);
}

// Round 8
// 2086.055 us; speedup vs baseline: 2.3554x; 1.6579x over previous
//
#include <hip/hip_runtime.h>
#include <cstdint>

#define TT 512

typedef unsigned short u16;
typedef uint32_t u32;
typedef float    floatx4 __attribute__((ext_vector_type(4)));
typedef _Float16 f16x8   __attribute__((ext_vector_type(8)));
typedef short    short8  __attribute__((ext_vector_type(8)));
typedef u32      u32x4   __attribute__((ext_vector_type(4)));
typedef u32      u32x2   __attribute__((ext_vector_type(2)));

__device__ __forceinline__ float sigm(float x)  { return 1.0f / (1.0f + __expf(-x)); }
__device__ __forceinline__ float tanh_(float x) { return 2.0f / (1.0f + __expf(-2.0f * x)) - 1.0f; }
__device__ __forceinline__ u16 f2h(float f) {           // f32 -> fp16 bits (RNE)
    union { _Float16 h; u16 u; } v; v.h = (_Float16)f; return v.u;
}
#define F16V(p) (*(const f16x8*)(const void*)(p))

// ---- r7-proven protocol: stamped words [stamp16|f16] / [f32|stamp32], sc1
// fire-and-forget stores, consumer stamp-check retry. 1 coherence trip/phase.
// r7 lesson: trips and compute volume are NOT the bottleneck; the per-phase
// 192KB L2 weight stream + latency exposure is -> this round: weights in LDS.
__device__ __forceinline__ void st32_dev(u32* p, u32 v) {
    asm volatile("global_store_dword %0, %1, off sc1" :: "v"(p), "v"(v) : "memory");
}
__device__ __forceinline__ void st64_dev(u32* p, u32 lo, u32 hi) {
    u32x2 d; d[0] = lo; d[1] = hi;
    asm volatile("global_store_dwordx2 %0, %1, off sc1" :: "v"(p), "v"(d) : "memory");
}
__device__ __forceinline__ u32x4 ld128_dev(const u32x4* p) {   // pipelined: no wait
    u32x4 v;
    asm volatile("global_load_dwordx4 %0, %1, off sc1" : "=v"(v) : "v"(p));
    return v;
}
__device__ __forceinline__ u32 ld32_dev(const u32* p) {        // pipelined: no wait
    u32 v;
    asm volatile("global_load_dword %0, %1, off sc1" : "=v"(v) : "v"(p));
    return v;
}
__device__ __forceinline__ void vmcnt0() { asm volatile("s_waitcnt vmcnt(0)" ::: "memory"); }
#define KEEP(x) asm volatile("" : "+v"(x))   // consume-after-wait fence (rule #18)

// zero stamps each launch (stale stamps 1..513 would false-accept).
// hx0 (512KB) + hx1 (512KB) + posc (64KB) contiguous = 69632 dwordx4.
__global__ void zero_ws(u32* base, int n4) {
    u32x4 z = {0u, 0u, 0u, 0u};
    for (int i = blockIdx.x * blockDim.x + threadIdx.x; i < n4; i += gridDim.x * blockDim.x)
        asm volatile("global_store_dwordx4 %0, %1, off sc1"
                     :: "v"(((u32x4*)base) + i), "v"(z) : "memory");
}

#define MFMA_(A_, B_, ACC) ACC = __builtin_amdgcn_mfma_f32_16x16x32_f16(A_, B_, ACC, 0, 0, 0)
#define MS1(ACC, GATE_) { f16x8 A_ = F16V(fs0 + (GATE_) * 4096); MFMA_(A_, Bh, ACC); }
#define MS3(ACC, GATE_) { f16x8 A1_ = F16V(fs1 + (GATE_) * 4096); MFMA_(A1_, Bh, ACC); \
    f16x8 A2_ = F16V(fs2 + (GATE_) * 4096); MFMA_(A2_, Ch, ACC); }

#define GATE0(R) { \
    const int d_ = dg16 + 4 * q + (R); \
    float zi_ = Zi[R] + bs[0][d_], zf_ = Zf[R] + bs[1][d_]; \
    float zg_ = Zg[R] + bs[2][d_], zo_ = Zo[R] + bs[3][d_]; \
    float c_  = sigm(zf_) * cv[R] + sigm(zi_) * tanh_(zg_); cv[R] = c_; \
    float hv_ = sigm(zo_) * tanh_(c_); \
    st32_dev(&hx0w[d_ * 16 + bq], tgthi | (u32)f2h(hv_)); }
#define GATE1(R) { \
    const int d_ = dg16 + 4 * q + (R); \
    float zi_ = Yi[R] + bs[0][d_], zf_ = Yf[R] + bs[1][d_]; \
    float zg_ = Yg[R] + bs[2][d_], zo_ = Yo[R] + bs[3][d_]; \
    float c_  = sigm(zf_) * cv[R] + sigm(zi_) * tanh_(zg_); cv[R] = c_; \
    float hv_ = sigm(zo_) * tanh_(c_); \
    st32_dev(&hx1w[d_ * 16 + bq], tgthi | (u32)f2h(hv_)); \
    part += hv_ * who_s[d_]; }

#define UNPACK0(v, i4) { const int d_ = (i4) >> 2, bb_ = ((i4) & 3) * 4; \
    h0f[bb_ + 0][d_] = (u16)((v)[0] & 0xFFFFu); \
    h0f[bb_ + 1][d_] = (u16)((v)[1] & 0xFFFFu); \
    h0f[bb_ + 2][d_] = (u16)((v)[2] & 0xFFFFu); \
    h0f[bb_ + 3][d_] = (u16)((v)[3] & 0xFFFFu); }
#define UNPACK1(v, i4) { const int d_ = (i4) >> 2, bb_ = ((i4) & 3) * 4; \
    h1f[bb_ + 0][d_] = (u16)((v)[0] & 0xFFFFu); \
    h1f[bb_ + 1][d_] = (u16)((v)[1] & 0xFFFFu); \
    h1f[bb_ + 2][d_] = (u16)((v)[2] & 0xFFFFu); \
    h1f[bb_ + 3][d_] = (u16)((v)[3] & 0xFFFFu); }
#define STALE4(v) (((v)[0] ^ tgthi) | ((v)[1] ^ tgthi) | ((v)[2] ^ tgthi) | ((v)[3] ^ tgthi))

// 256 blocks = 16 groups x (8 L0-slices + 8 L1-slices), 128 threads, 1 block/CU.
// Weights LDS-resident: L0 64KB (W_hh0 slice), L1 128KB (W_ih1+W_hh1 slice).
// L0 block p: compute h0(p+1) from h0f, store stamped; readback full hx0 +
//   8 hx1 stamp SAMPLES (>=, monotone) for ring-depth-2 pacing vs L1 cohort.
// L1 block p>=1: compute h1(p) from h0f,h1f; store hx1 + posc; readback full
//   hx0 + hx1 (+posc for the jl==0 out-assembly block).
__launch_bounds__(128, 1)
__global__ void lstm_wave(const float* __restrict__ latent, const float* __restrict__ W_lh,
                          const float* __restrict__ b_lh,
                          const float* __restrict__ W_hh0,
                          const float* __restrict__ b_ih0, const float* __restrict__ b_hh0,
                          const float* __restrict__ W_ih1, const float* __restrict__ W_hh1,
                          const float* __restrict__ b_ih1, const float* __restrict__ b_hh1,
                          const float* __restrict__ W_ho,  const float* __restrict__ b_ho,
                          u32* __restrict__ hx0, u32* __restrict__ hx1,
                          u32* __restrict__ posc, float* __restrict__ out)
{
    extern __shared__ __align__(16) char smem[];
    short* wlds     = (short*)smem;                          // <=128KB weight frags
    u16 (*h0f)[264] = (u16(*)[264])(smem + 131072);          // 8448 B
    u16 (*h1f)[264] = (u16(*)[264])(smem + 139520);          // 8448 B (L1 only)
    float (*bs)[256] = (float(*)[256])(smem + 147968);       // 4096 B (b0 or b1)
    float* who_s    = (float*)(smem + 152064);               // 1024 B (L1 only)

    const int tid  = threadIdx.x;      // 128 threads, 2 waves
    const int w    = tid >> 6;
    const int lane = tid & 63;
    const int bq   = lane & 15;
    const int q    = lane >> 4;
    const int g    = blockIdx.x & 15;  // batch group
    const int s16  = blockIdx.x >> 4;  // 0..15
    const int role = s16 >> 3;         // 0 = layer-0 block, 1 = layer-1 block
    const int jl   = s16 & 7;          // 32-dim slice within the layer
    const int bglo = g * 16;

    // ---- stage this block's weight slice f32->f16 into LDS (one-time)
    {
        const int nv = role ? 8192 : 4096;       // 8-float vectors
        for (int i = tid; i < nv; i += 128) {
            const int l8 = i & 63, s8 = (i >> 6) & 7, gate8 = (i >> 9) & 3;
            const int dgl = (i >> 11) & 1, G = (i >> 12) & 1;
            const float* W = role ? (G ? W_hh1 : W_ih1) : W_hh0;
            const int rowdim = jl * 32 + dgl * 16 + (l8 & 15);
            const float* src = W + (gate8 * 256 + rowdim) * 256 + s8 * 32 + (l8 >> 4) * 8;
            short8 v;
#pragma unroll
            for (int jj = 0; jj < 8; ++jj) v[jj] = (short)f2h(src[jj]);
            *(short8*)(wlds + l8 * 8 + s8 * 512 + gate8 * 4096 + dgl * 16384 + G * 32768) = v;
        }
    }
    for (int i = tid; i < 1024; i += 128)
        bs[i >> 8][i & 255] = role ? (b_ih1[i] + b_hh1[i]) : (b_ih0[i] + b_hh0[i]);
    if (role) { who_s[tid] = W_ho[tid]; who_s[tid + 128] = W_ho[tid + 128]; }

    // ---- h_init = latent @ W_lh.T + b_lh (fp32), rounded to fp16
    {
        const int b = tid >> 3, d0 = (tid & 7) * 32;
        const float* lr = latent + (bglo + b) * 128;
        for (int jj = 0; jj < 32; ++jj) {
            const int d = d0 + jj;
            const float* wr = W_lh + d * 128;
            float acc = b_lh[d];
            for (int c = 0; c < 128; c += 4) {
                float4 lv = *(const float4*)(lr + c);
                float4 wv = *(const float4*)(wr + c);
                acc += lv.x * wv.x + lv.y * wv.y + lv.z * wv.z + lv.w * wv.w;
            }
            u16 hb = f2h(acc);
            h0f[b][d] = hb;
            if (role) h1f[b][d] = hb;
        }
    }
    __syncthreads();

    const int dg16 = jl * 32 + w * 16;
    const short* fbA = wlds + w * 16384 + (size_t)lane * 8;  // L0: W_hh0; L1: W_ih1
    float cv[4] = {0.f, 0.f, 0.f, 0.f};
    const float bho = b_ho[0];

    if (role == 0) {
        // ================= layer-0 block: phases 0..TT-1 =================
        for (int p = 0; p < TT; ++p) {
            const int pb = p & 1;
            u32* hx0w = hx0 + pb * 65536 + g * 4096;
            const u32* hx1w = hx1 + pb * 65536 + g * 4096;
            const u32 tgthi = (u32)(p + 1) << 16;
            const u32 tgt32 = (u32)(p + 1);

            floatx4 Zi = {0.f,0.f,0.f,0.f}, Zf = {0.f,0.f,0.f,0.f};
            floatx4 Zg = {0.f,0.f,0.f,0.f}, Zo = {0.f,0.f,0.f,0.f};
#pragma unroll
            for (int s = 0; s < 8; ++s) {
                f16x8 Bh = F16V(&h0f[bq][s * 32 + q * 8]);
                const short* fs0 = fbA + s * 512;
                MS1(Zi, 0) MS1(Zf, 1) MS1(Zg, 2) MS1(Zo, 3)
            }
            GATE0(0) GATE0(1) GATE0(2) GATE0(3)
            if (p == TT - 1) break;          // final store issued; nothing more needed

            // readback h0(p+1) + pacing samples of L1 progress (monotone >=)
            u32x4 va0, va1, va2, va3, va4, va5, va6, va7;
            u32 pc = 0;
            const u32x4* s4a = (const u32x4*)hx0w;
#define ISSUE0() do { \
            va0 = ld128_dev(s4a + tid);       va1 = ld128_dev(s4a + tid + 128); \
            va2 = ld128_dev(s4a + tid + 256); va3 = ld128_dev(s4a + tid + 384); \
            va4 = ld128_dev(s4a + tid + 512); va5 = ld128_dev(s4a + tid + 640); \
            va6 = ld128_dev(s4a + tid + 768); va7 = ld128_dev(s4a + tid + 896); \
            if ((lane < 8) && p) pc = ld32_dev(hx1w + lane * 512); \
        } while (0)
            ISSUE0();
            __syncthreads();                 // both waves done reading h0f
            int it = 0;
            while (true) {
                vmcnt0();
                KEEP(va0); KEEP(va1); KEEP(va2); KEEP(va3);
                KEEP(va4); KEEP(va5); KEEP(va6); KEEP(va7); KEEP(pc);
                u32 sh = STALE4(va0) | STALE4(va1) | STALE4(va2) | STALE4(va3)
                       | STALE4(va4) | STALE4(va5) | STALE4(va6) | STALE4(va7);
                const bool okp = ((lane < 8) && p) ? ((pc >> 16) >= tgt32) : true;
                const bool ok = ((sh & 0xFFFF0000u) == 0u) && okp;
                if (__ballot(ok) == 0xFFFFFFFFFFFFFFFFull) break;
                if (++it > 20000) break;     // finite-wrong, never hang
                ISSUE0();
            }
#undef ISSUE0
            UNPACK0(va0, tid);       UNPACK0(va1, tid + 128);
            UNPACK0(va2, tid + 256); UNPACK0(va3, tid + 384);
            UNPACK0(va4, tid + 512); UNPACK0(va5, tid + 640);
            UNPACK0(va6, tid + 768); UNPACK0(va7, tid + 896);
            __syncthreads();                 // h0f ready for next phase
        }
    } else {
        // ================= layer-1 block: phases 0..TT =================
        const short* fbB = fbA;              // fs2 = fs1 + 32768 handles W_hh1
        const bool isout = (jl == 0);
        for (int p = 0; p <= TT; ++p) {
            const int pb = p & 1;
            const u32* hx0w = hx0 + pb * 65536 + g * 4096;
            u32* hx1w = hx1 + pb * 65536 + g * 4096;
            u32* poscw = posc + (pb * 16 + g) * 512;
            const u32 tgthi = (u32)(p + 1) << 16;
            const u32 tgt32 = (u32)(p + 1);

            if (p >= 1) {
                floatx4 Yi = {0.f,0.f,0.f,0.f}, Yf = {0.f,0.f,0.f,0.f};
                floatx4 Yg = {0.f,0.f,0.f,0.f}, Yo = {0.f,0.f,0.f,0.f};
#pragma unroll
                for (int s = 0; s < 8; ++s) {
                    f16x8 Bh = F16V(&h0f[bq][s * 32 + q * 8]);
                    f16x8 Ch = F16V(&h1f[bq][s * 32 + q * 8]);
                    const short* fs1 = fbB + s * 512;
                    const short* fs2 = fs1 + 32768;
                    MS3(Yi, 0) MS3(Yf, 1) MS3(Yg, 2) MS3(Yo, 3)
                }
                float part = 0.0f;
                GATE1(0) GATE1(1) GATE1(2) GATE1(3)
                part += __shfl_xor(part, 16, 64);
                part += __shfl_xor(part, 32, 64);
                if (q == 0)
                    st64_dev(poscw + (bq * 16 + jl * 2 + w) * 2,
                             __float_as_uint(part), tgt32);
            }

            const bool rdA = p < TT;
            const bool rdB = (p >= 1) && (p < TT);
            const bool rdP = isout && (p >= 1) && (tid < 16);
            u32x4 va0, va1, va2, va3, va4, va5, va6, va7;
            u32x4 vb0, vb1, vb2, vb3, vb4, vb5, vb6, vb7;
            u32x4 po0, po1, po2, po3, po4, po5, po6, po7;
            const u32x4* s4a = (const u32x4*)hx0w;
            const u32x4* s4b = (const u32x4*)hx1w;
            const u32x4* s4p = (const u32x4*)poscw + tid * 8;
#define ISSUE1() do { \
            if (rdA) { \
                va0 = ld128_dev(s4a + tid);       va1 = ld128_dev(s4a + tid + 128); \
                va2 = ld128_dev(s4a + tid + 256); va3 = ld128_dev(s4a + tid + 384); \
                va4 = ld128_dev(s4a + tid + 512); va5 = ld128_dev(s4a + tid + 640); \
                va6 = ld128_dev(s4a + tid + 768); va7 = ld128_dev(s4a + tid + 896); } \
            if (rdB) { \
                vb0 = ld128_dev(s4b + tid);       vb1 = ld128_dev(s4b + tid + 128); \
                vb2 = ld128_dev(s4b + tid + 256); vb3 = ld128_dev(s4b + tid + 384); \
                vb4 = ld128_dev(s4b + tid + 512); vb5 = ld128_dev(s4b + tid + 640); \
                vb6 = ld128_dev(s4b + tid + 768); vb7 = ld128_dev(s4b + tid + 896); } \
            if (rdP) { \
                po0 = ld128_dev(s4p);     po1 = ld128_dev(s4p + 1); \
                po2 = ld128_dev(s4p + 2); po3 = ld128_dev(s4p + 3); \
                po4 = ld128_dev(s4p + 4); po5 = ld128_dev(s4p + 5); \
                po6 = ld128_dev(s4p + 6); po7 = ld128_dev(s4p + 7); } \
        } while (0)
            ISSUE1();
            __syncthreads();                 // both waves done reading h0f/h1f
            int it = 0;
            while (true) {
                vmcnt0();
                u32 sh = 0, sf = 0;
                if (rdA) {
                    KEEP(va0); KEEP(va1); KEEP(va2); KEEP(va3);
                    KEEP(va4); KEEP(va5); KEEP(va6); KEEP(va7);
                    sh |= STALE4(va0) | STALE4(va1) | STALE4(va2) | STALE4(va3)
                        | STALE4(va4) | STALE4(va5) | STALE4(va6) | STALE4(va7);
                }
                if (rdB) {
                    KEEP(vb0); KEEP(vb1); KEEP(vb2); KEEP(vb3);
                    KEEP(vb4); KEEP(vb5); KEEP(vb6); KEEP(vb7);
                    sh |= STALE4(vb0) | STALE4(vb1) | STALE4(vb2) | STALE4(vb3)
                        | STALE4(vb4) | STALE4(vb5) | STALE4(vb6) | STALE4(vb7);
                }
                if (rdP) {
                    KEEP(po0); KEEP(po1); KEEP(po2); KEEP(po3);
                    KEEP(po4); KEEP(po5); KEEP(po6); KEEP(po7);
                    sf |= (po0[1] ^ tgt32) | (po0[3] ^ tgt32) | (po1[1] ^ tgt32) | (po1[3] ^ tgt32)
                        | (po2[1] ^ tgt32) | (po2[3] ^ tgt32) | (po3[1] ^ tgt32) | (po3[3] ^ tgt32)
                        | (po4[1] ^ tgt32) | (po4[3] ^ tgt32) | (po5[1] ^ tgt32) | (po5[3] ^ tgt32)
                        | (po6[1] ^ tgt32) | (po6[3] ^ tgt32) | (po7[1] ^ tgt32) | (po7[3] ^ tgt32);
                }
                const bool ok = ((sh & 0xFFFF0000u) == 0u) && (sf == 0u);
                if (__ballot(ok) == 0xFFFFFFFFFFFFFFFFull) break;
                if (++it > 20000) break;     // finite-wrong, never hang
                ISSUE1();
            }
#undef ISSUE1
            if (rdA) {
                UNPACK0(va0, tid);       UNPACK0(va1, tid + 128);
                UNPACK0(va2, tid + 256); UNPACK0(va3, tid + 384);
                UNPACK0(va4, tid + 512); UNPACK0(va5, tid + 640);
                UNPACK0(va6, tid + 768); UNPACK0(va7, tid + 896);
            }
            if (rdB) {
                UNPACK1(vb0, tid);       UNPACK1(vb1, tid + 128);
                UNPACK1(vb2, tid + 256); UNPACK1(vb3, tid + 384);
                UNPACK1(vb4, tid + 512); UNPACK1(vb5, tid + 640);
                UNPACK1(vb6, tid + 768); UNPACK1(vb7, tid + 896);
            }
            if (rdP) {                       // assemble out[t = p-1]
                float o = bho;
                o += __uint_as_float(po0[0]) + __uint_as_float(po0[2]);
                o += __uint_as_float(po1[0]) + __uint_as_float(po1[2]);
                o += __uint_as_float(po2[0]) + __uint_as_float(po2[2]);
                o += __uint_as_float(po3[0]) + __uint_as_float(po3[2]);
                o += __uint_as_float(po4[0]) + __uint_as_float(po4[2]);
                o += __uint_as_float(po5[0]) + __uint_as_float(po5[2]);
                o += __uint_as_float(po6[0]) + __uint_as_float(po6[2]);
                o += __uint_as_float(po7[0]) + __uint_as_float(po7[2]);
                out[(bglo + tid) * TT + (p - 1)] = o;
            }
            __syncthreads();                 // LDS planes ready for next phase
        }
    }
}

extern "C" void kernel_launch(void* const* d_in, const int* in_sizes, int n_in,
                              void* d_out, int out_size, void* d_ws, size_t ws_size,
                              hipStream_t stream)
{
    const float* latent = (const float*)d_in[0];
    const float* W_lh   = (const float*)d_in[1];
    const float* b_lh   = (const float*)d_in[2];
    // d_in[3] = W_ih0: unused (layer-0 inputs are all-zero)
    const float* W_hh0  = (const float*)d_in[4];
    const float* b_ih0  = (const float*)d_in[5];
    const float* b_hh0  = (const float*)d_in[6];
    const float* W_ih1  = (const float*)d_in[7];
    const float* W_hh1  = (const float*)d_in[8];
    const float* b_ih1  = (const float*)d_in[9];
    const float* b_hh1  = (const float*)d_in[10];
    const float* W_ho   = (const float*)d_in[11];
    const float* b_ho   = (const float*)d_in[12];

    char* ws = (char*)d_ws;
    u32*   hx0  = (u32*)ws;                       //   524,288 B (2 parities, [stamp16|f16])
    u32*   hx1  = (u32*)(ws + 524288);            //   524,288 B
    u32*   posc = (u32*)(ws + 1048576);           //    65,536 B (2 par x 16g x 512 u32)
    // total 1,114,112 B

    // opt into >64KB dynamic LDS (153,088 B: 128KB wfrag + planes + biases)
    hipFuncSetAttribute((const void*)lstm_wave,
                        hipFuncAttributeMaxDynamicSharedMemorySize, 153088);

    zero_ws<<<dim3(128), dim3(256), 0, stream>>>(hx0, 69632);
    lstm_wave<<<dim3(256), dim3(128), 153088, stream>>>(latent, W_lh, b_lh,
                                                        W_hh0, b_ih0, b_hh0,
                                                        W_ih1, W_hh1, b_ih1, b_hh1,
                                                        W_ho, b_ho,
                                                        hx0, hx1, posc,
                                                        (float*)d_out);
}